// Round 7
// baseline (221.475 us; speedup 1.0000x reference)
//
#include <hip/hip_runtime.h>
#include <hip/hip_bf16.h>

typedef float v4f __attribute__((ext_vector_type(4)));
typedef short v8s __attribute__((ext_vector_type(8)));

// ---- workspace layout ----
// float indices:
#define WS_STAT2   0        // 64   conv2 per-ic mean-of-max
#define WS_STATL   64       // 1024 (unused now; kept for layout stability)
#define WS_B1      1088     // 64
#define WS_B2      1152     // 64
#define WS_WL      1216     // 10240
#define WS_BL      11456    // 10
#define WS_IMAX    11520    // 2048 per-image max|x|
// byte offsets:
#define WS_W1F_B   54272    // 4096 bf16 conv1 weight frags [ot][q][m16][j], oc = m16*4+ot
#define WS_WP2_B   62464    // 25*64*64 bf16 conv2 weights, fragment order [uv][kc][ot][quad][m16][j]
#define WS_P1_B    267264   // 2048*144*64 bf16 pooled1 NHWC
#define WS_P2_B    38016000 // 2048*1024 fp32 pooled2
// scratch aliases (stream-ordered reuse, no extra footprint):
#define WS_C1MAX_F 9504000  // = P2 base as float idx; conv1 per-image ch-max [n][64]
#define WS_LPART_F 66816    // = P1 base as float idx; statl partials [64][1024]
// total ~46.4 MB (unchanged)

// per-image max|x|: 512 blocks x 4 waves, wave = 1 image.
__global__ void k_stat1(const float* __restrict__ x, float* ws) {
    int tid = threadIdx.x;
    int wv = tid >> 6, lane = tid & 63;
    int n = blockIdx.x * 4 + wv;
    const float* p = x + n * 784;
    float m = 0.f;
    for (int i = lane; i < 784; i += 64) m = fmaxf(m, fabsf(p[i]));
#pragma unroll
    for (int off = 32; off; off >>= 1) m = fmaxf(m, __shfl_xor(m, off, 64));
    if (lane == 0) ws[WS_IMAX + n] = m;
}

// conv1 SCINOL weights -> bf16 B-fragments [ot][q][m16][j] with oc = m16*4+ot
__global__ void k_prepw1(const float* __restrict__ w0, const float* __restrict__ S2,
                         const float* __restrict__ G, const float* __restrict__ eta,
                         const float* __restrict__ wM,
                         const float* __restrict__ b0, const float* __restrict__ bS2,
                         const float* __restrict__ bG, const float* __restrict__ beta,
                         float* ws) {
    __shared__ float red[256];
    int tid = threadIdx.x;
    float p = 0.f;
    for (int i = tid; i < 2048; i += 256) p += ws[WS_IMAX + i];
    red[tid] = p;
    __syncthreads();
    for (int s = 128; s > 0; s >>= 1) {
        if (tid < s) red[tid] += red[tid + s];
        __syncthreads();
    }
    float M = fmaxf(red[0] * (1.f / 2048.f), wM[0]);

    int i = blockIdx.x * 256 + tid;
    if (i < 4096) {
        int j = i & 7, m16 = (i >> 3) & 15, q = (i >> 7) & 3, ot = i >> 9;
        int tap = q * 8 + j, oc = m16 * 4 + ot;
        float v = 0.f;
        if (tap < 25) {
            int s = oc * 25 + tap;
            float g = G[s];
            float den = sqrtf(S2[s] + M * M);
            float inv = 1.f / den;
            float th = fminf(fmaxf(g * inv, -1.f), 1.f);
            v = w0[s] + ((g != 0.f) ? th * 0.5f * inv * eta[s] : 0.f);
        }
        ((__hip_bfloat16*)((char*)ws + WS_W1F_B))[i] = __float2bfloat16(v);
    } else if (i < 4160) {
        int c = i - 4096;
        float g = bG[c];
        float den = sqrtf(bS2[c] + 1.f);
        float inv = 1.f / den;
        float th = fminf(fmaxf(g * inv, -1.f), 1.f);
        ws[WS_B1 + c] = b0[c] + ((g != 0.f) ? th * 0.5f * inv * beta[c] : 0.f);
    }
}

// conv1 via MFMA implicit GEMM. Block = 256 thr (4 waves) = 1 image.
// Image staged as bf16 (rounding point unchanged -> identical numerics).
// Per-image channel maxima -> WS_C1MAX_F (plain stores; NO device atomics).
__global__ void __launch_bounds__(256)
k_conv1(const float* __restrict__ x, float* ws, __hip_bfloat16* __restrict__ pool1) {
    __shared__ __align__(16) ushort sXh[1024];   // 28x28 image as bf16 + zero pad
    __shared__ int sMax[64];
    int n = blockIdx.x, tid = threadIdx.x;
    int wv = tid >> 6, lane = tid & 63;
    int m16 = lane & 15, quad = lane >> 4;

    {   // stage image (784 floats -> bf16) + zero pad to 1024
        const float4* src = (const float4*)(x + (size_t)n * 784);
        float4 v = {0.f, 0.f, 0.f, 0.f};
        if (tid < 196) v = src[tid];
        ushort4 h;
        h.x = __bfloat16_as_ushort(__float2bfloat16(v.x));
        h.y = __bfloat16_as_ushort(__float2bfloat16(v.y));
        h.z = __bfloat16_as_ushort(__float2bfloat16(v.z));
        h.w = __bfloat16_as_ushort(__float2bfloat16(v.w));
        ((ushort4*)sXh)[tid] = h;
    }
    if (tid < 64) sMax[tid] = 0;

    const ushort* wfrag = (const ushort*)((const char*)ws + WS_W1F_B);
    v8s bfr[4];
#pragma unroll
    for (int ot = 0; ot < 4; ++ot)
        bfr[ot] = *(const v8s*)(wfrag + ((ot * 4 + quad) * 16 + m16) * 8);
    float4 bias = *(const float4*)(ws + WS_B1 + m16 * 4);

    int dj[8];
#pragma unroll
    for (int j = 0; j < 8; ++j) {
        int tap = quad * 8 + j;
        int u = (tap * 13) >> 6;
        dj[j] = tap + 23 * u;
    }

    int W0 = wv * 36 + (m16 >> 2);
    int wy = (W0 * 171) >> 11;
    int wx = W0 - wy * 12;
    int coff = 28 * ((m16 >> 1) & 1) + (m16 & 1);

    __syncthreads();

    float vmax[4] = {0.f, 0.f, 0.f, 0.f};
    ushort* op = (ushort*)(pool1 + (size_t)n * 9216);

    ushort g[8];
    {
        int base = 56 * wy + 2 * wx + coff;
#pragma unroll
        for (int j = 0; j < 8; ++j) g[j] = sXh[base + dj[j]];
    }
    for (int mt = 0; mt < 9; ++mt) {
        union { v8s v; ushort us[8]; } ua;
#pragma unroll
        for (int j = 0; j < 8; ++j) ua.us[j] = g[j];

        wx += 4;
        if (wx >= 12) { wx -= 12; ++wy; }
        if (mt < 8) {
            int nb = 56 * wy + 2 * wx + coff;
#pragma unroll
            for (int j = 0; j < 8; ++j) g[j] = sXh[nb + dj[j]];
        }

        v4f z = {0.f, 0.f, 0.f, 0.f};
        v4f acc[4];
#pragma unroll
        for (int ot = 0; ot < 4; ++ot)
            acc[ot] = __builtin_amdgcn_mfma_f32_16x16x32_bf16(ua.v, bfr[ot], z, 0, 0, 0);

        int Wd = (wv * 9 + mt) * 4 + quad;
        ushort4 pk;
#pragma unroll
        for (int ot = 0; ot < 4; ++ot) {
            v4f a = acc[ot];
            float m = fmaxf(fmaxf(a[0], a[1]), fmaxf(a[2], a[3]));
            float pv = fmaxf(m + bias[ot], 0.f);
            vmax[ot] = fmaxf(vmax[ot], pv);
            ((ushort*)&pk)[ot] = __bfloat16_as_ushort(__float2bfloat16(pv));
        }
        *(ushort4*)(op + Wd * 64 + m16 * 4) = pk;
    }

#pragma unroll
    for (int ot = 0; ot < 4; ++ot) {
        float m = vmax[ot];
        m = fmaxf(m, __shfl_xor(m, 16, 64));
        m = fmaxf(m, __shfl_xor(m, 32, 64));
        if (lane < 16) atomicMax(&sMax[lane * 4 + ot], __float_as_int(m));
    }
    __syncthreads();
    if (tid < 64) ws[WS_C1MAX_F + n * 64 + tid] = __int_as_float(sMax[tid]);
}

// reduce conv1 per-image channel maxima -> per-channel batch mean. 64 blocks, 1/ch.
__global__ void k_stat2red(float* ws) {
    __shared__ float red[256];
    int c = blockIdx.x, t = threadIdx.x;
    float s = 0.f;
    for (int n = t; n < 2048; n += 256) s += ws[WS_C1MAX_F + n * 64 + c];
    red[t] = s;
    __syncthreads();
    for (int k = 128; k > 0; k >>= 1) {
        if (t < k) red[t] += red[t + k];
        __syncthreads();
    }
    if (t == 0) ws[WS_STAT2 + c] = red[0] * (1.f / 2048.f);
}

// conv2 SCINOL weights -> bf16 in MFMA fragment order [uv][kc][ot][quad][m16][j]
__global__ void k_prepw2(const float* __restrict__ w0, const float* __restrict__ S2,
                         const float* __restrict__ G, const float* __restrict__ eta,
                         const float* __restrict__ wM,
                         const float* __restrict__ b0, const float* __restrict__ bS2,
                         const float* __restrict__ bG, const float* __restrict__ beta,
                         float* ws, __hip_bfloat16* __restrict__ wp2) {
    int i = blockIdx.x * 256 + threadIdx.x;  // exactly 102400
    int j = i & 7, m16 = (i >> 3) & 15, quad = (i >> 7) & 3;
    int ot = (i >> 9) & 3, kc = (i >> 11) & 1, uv = i >> 12;
    int oc = ot * 16 + m16, ic = kc * 32 + quad * 8 + j;
    int s = oc * 1600 + ic * 25 + uv;
    float M = fmaxf(ws[WS_STAT2 + ic], wM[ic]);
    float g = G[s];
    float den = sqrtf(S2[s] + M * M);
    float inv = 1.f / den;
    float th = fminf(fmaxf(g * inv, -1.f), 1.f);
    float v = w0[s] + ((g != 0.f) ? th * 0.5f * inv * eta[s] : 0.f);
    wp2[i] = __float2bfloat16(v);
    if (blockIdx.x == 0 && threadIdx.x < 64) {
        int c = threadIdx.x;
        float gb = bG[c];
        float den2 = sqrtf(bS2[c] + 1.f);
        float inv2 = 1.f / den2;
        float th2 = fminf(fmaxf(gb * inv2, -1.f), 1.f);
        ws[WS_B2 + c] = b0[c] + ((gb != 0.f) ? th2 * 0.5f * inv2 * beta[c] : 0.f);
    }
}

// conv2 implicit GEMM, v7: block = 384 thr (6 waves) = 3 images; wave =
// (image, kc-half). vs v5: B-LDS is double-buffered (2x8KB) -> ONE barrier
// per uv (27 total vs 50); LDS = 54+16 = 70KB -> 2 blocks/CU = 12 waves/CU
// (vs 8). Per-wave uv work halves (4 A-reads + 4 B-reads + 16 MFMA); kc
// partial sums combined once at the end through LDS (reuses sImg). B global
// traffic 683 x 200KB = 137MB (L3-cheap). No device atomics.
__global__ void __launch_bounds__(384, 3)
k_conv2(const ushort* __restrict__ pool1, const ushort* __restrict__ wp2,
        const float* __restrict__ ws, float* __restrict__ pool2) {
    __shared__ __align__(16) ushort sImg[3 * 9216];   // 54KB: 3 images, swizzled
    __shared__ __align__(16) ushort sB[2][4096];      // 16KB: B dbuf (one uv each)
    int tid = threadIdx.x;
    int wv = tid >> 6, lane = tid & 63;
    int n0 = blockIdx.x * 3;
    int nimg = min(3, 2048 - n0);

    {   // stage up to 3 images: chunks (r,col) -> r*8 + (col^(r&7)), 1152 uint4/img
        const uint4* src = (const uint4*)(pool1 + (size_t)n0 * 9216);
        uint4* dst = (uint4*)sImg;
#pragma unroll
        for (int i = 0; i < 9; ++i) {
            int c = tid + i * 384;              // 0..3455
            int img = c / 1152;
            int w = c - img * 1152;
            int r = w >> 3, col = w & 7;
            if (img < nimg)
                dst[img * 1152 + r * 8 + (col ^ (r & 7))] = src[c];
        }
    }
    // stage B for uv=0 into sB[0] (512 uint4)
    const uint4* bsrc = (const uint4*)wp2;
    {
        ((uint4*)sB[0])[tid] = bsrc[tid];
        if (tid < 128) ((uint4*)sB[0])[384 + tid] = bsrc[384 + tid];
    }

    int m16 = lane & 15, quad = lane >> 4;
    int x0 = m16 & 7, yb = m16 >> 3;
    int rbase = yb * 12 + x0;
    int img_l = wv >> 1, kc = wv & 1;
    int img_e = (img_l < nimg) ? img_l : 0;     // tail waves compute on img0, discard
    const ushort* simg = sImg + img_e * 9216;

    v4f acc[4][4];
#pragma unroll
    for (int i = 0; i < 4; ++i)
#pragma unroll
        for (int j = 0; j < 4; ++j) acc[i][j] = (v4f){0.f, 0.f, 0.f, 0.f};

    __syncthreads();    // images + sB[0] ready

    int cur = 0;
    for (int uv = 0; uv < 25; ++uv) {
        uint4 nr0, nr1;
        if (uv < 24) {   // prefetch next uv's B to regs (hidden under MFMAs)
            const uint4* nb = bsrc + (uv + 1) * 512;
            nr0 = nb[tid];
            if (tid < 128) nr1 = nb[384 + tid];
        }
        int u = (uv * 13) >> 6;      // uv / 5
        int v = uv - u * 5;
        int r0 = rbase + u * 12 + v;

        v8s pA[4], pB[4];
#pragma unroll
        for (int pt = 0; pt < 4; ++pt) {
            int row = r0 + pt * 24;
            int rs = row & 7;
            pA[pt] = *(const v8s*)(simg + row * 64 + (((kc * 4 + quad) ^ rs) << 3));
        }
#pragma unroll
        for (int ot = 0; ot < 4; ++ot)
            pB[ot] = *(const v8s*)(sB[cur] + (kc * 4 + ot) * 512 + lane * 8);
#pragma unroll
        for (int pt = 0; pt < 4; ++pt)
#pragma unroll
            for (int ot = 0; ot < 4; ++ot)
                acc[pt][ot] = __builtin_amdgcn_mfma_f32_16x16x32_bf16(
                    pA[pt], pB[ot], acc[pt][ot], 0, 0, 0);

        if (uv < 24) {   // publish next uv into the OTHER buffer (no reader this step)
            ((uint4*)sB[cur ^ 1])[tid] = nr0;
            if (tid < 128) ((uint4*)sB[cur ^ 1])[384 + tid] = nr1;
        }
        __syncthreads();             // single barrier per uv
        cur ^= 1;
    }

    // combine kc partials: kc0 waves write acc to LDS (reuse sImg), kc1 adds.
    float* ex = (float*)sImg;        // 3 x 16KB = 48KB <= 54KB
    if (kc == 0 && img_l < nimg) {
#pragma unroll
        for (int pt = 0; pt < 4; ++pt)
#pragma unroll
            for (int ot = 0; ot < 4; ++ot)
                *(v4f*)(ex + img_l * 4096 + (pt * 4 + ot) * 256 + lane * 4) = acc[pt][ot];
    }
    __syncthreads();
    if (kc == 1 && img_l < nimg) {
#pragma unroll
        for (int pt = 0; pt < 4; ++pt)
#pragma unroll
            for (int ot = 0; ot < 4; ++ot) {
                v4f p = *(const v4f*)(ex + img_l * 4096 + (pt * 4 + ot) * 256 + lane * 4);
                acc[pt][ot] += p;
            }

        // epilogue: bias + relu + 2x2 maxpool -> pooled2[n][oc*16+py*4+px] fp32
        int n = n0 + img_l;
        float bv[4];
#pragma unroll
        for (int ot = 0; ot < 4; ++ot) bv[ot] = ws[WS_B2 + ot * 16 + m16];
        float* outp = pool2 + (size_t)n * 1024;
#pragma unroll
        for (int pt = 0; pt < 4; ++pt)
#pragma unroll
            for (int ot = 0; ot < 4; ++ot) {
                v4f a = acc[pt][ot];
                float m01 = fmaxf(a[0], a[1]);
                float m23 = fmaxf(a[2], a[3]);
                m01 = fmaxf(m01, __shfl_xor(m01, 32, 64));
                m23 = fmaxf(m23, __shfl_xor(m23, 32, 64));
                if (lane < 32) {
                    int oc = ot * 16 + m16;
                    int f = oc * 16 + pt * 4 + (quad & 1) * 2;
                    outp[f] = fmaxf(m01 + bv[ot], 0.f);
                    outp[f + 1] = fmaxf(m23 + bv[ot], 0.f);
                }
            }
    }
}

// per-feature partial sums over batch; 64 blocks x 32 images, plain stores.
__global__ void k_statl(const float* __restrict__ pool2, float* ws) {
    int b = blockIdx.x, tid = threadIdx.x;
    float4 s = {0.f, 0.f, 0.f, 0.f};
    for (int im = 0; im < 32; ++im) {
        float4 v = ((const float4*)(pool2 + (size_t)(b * 32 + im) * 1024))[tid];
        s.x += v.x; s.y += v.y; s.z += v.z; s.w += v.w;
    }
    ((float4*)(ws + WS_LPART_F + b * 1024))[tid] = s;
}

// linear weights; folds the 64-partial statl reduction inline (no separate kernel)
__global__ void k_prepwl(const float* __restrict__ w0, const float* __restrict__ S2,
                         const float* __restrict__ G, const float* __restrict__ eta,
                         const float* __restrict__ wM,
                         const float* __restrict__ b0, const float* __restrict__ bS2,
                         const float* __restrict__ bG, const float* __restrict__ beta,
                         float* ws) {
    int i = blockIdx.x * 256 + threadIdx.x;
    if (i < 10240) {
        int f = i & 1023;
        float s = 0.f;
#pragma unroll
        for (int b = 0; b < 64; ++b) s += ws[WS_LPART_F + b * 1024 + f];
        float stat = s * (1.f / 2048.f);
        float M = fmaxf(wM[i], stat);
        float s2 = S2[i];
        float den = sqrtf(s2 + M * M);
        float inv = 1.f / den;
        float th = fminf(fmaxf(G[i] * inv, -1.f), 1.f);
        ws[WS_WL + i] = w0[i] + ((s2 != 0.f) ? th * 0.5f * inv * eta[i] : 0.f);  // cond = wS2 != 0
    } else if (i < 10250) {
        int c = i - 10240;
        float s2 = bS2[c];
        float den = sqrtf(s2 + 1.f);
        float inv = 1.f / den;
        float th = fminf(fmaxf(bG[c] * inv, -1.f), 1.f);
        ws[WS_BL + c] = b0[c] + ((s2 != 0.f) ? th * 0.5f * inv * beta[c] : 0.f);  // cond = bS2 != 0
    }
}

// (2048,1024) x (1024,10)^T + b: wave per image, lane-strided features
__global__ void k_linear(const float* __restrict__ pool2, const float* __restrict__ ws,
                         float* __restrict__ out) {
    int tid = threadIdx.x;
    int wv = tid >> 6, lane = tid & 63;
    int n = blockIdx.x * 4 + wv;
    const float* hp = pool2 + (size_t)n * 1024;
    float h[16];
#pragma unroll
    for (int j = 0; j < 16; ++j) h[j] = hp[j * 64 + lane];
    for (int oc = 0; oc < 10; ++oc) {
        const float* wp = ws + WS_WL + oc * 1024;
        float d = 0.f;
#pragma unroll
        for (int j = 0; j < 16; ++j) d = fmaf(h[j], wp[j * 64 + lane], d);
#pragma unroll
        for (int off = 32; off; off >>= 1) d += __shfl_xor(d, off, 64);
        if (lane == 0) out[n * 10 + oc] = d + ws[WS_BL + oc];
    }
}

extern "C" void kernel_launch(void* const* d_in, const int* in_sizes, int n_in,
                              void* d_out, int out_size, void* d_ws, size_t ws_size,
                              hipStream_t stream) {
    const float* x = (const float*)d_in[0];
    float* ws = (float*)d_ws;
    __hip_bfloat16* wp2 = (__hip_bfloat16*)((char*)d_ws + WS_WP2_B);
    __hip_bfloat16* p1 = (__hip_bfloat16*)((char*)d_ws + WS_P1_B);
    float* p2 = (float*)((char*)d_ws + WS_P2_B);
    float* out = (float*)d_out;

    k_stat1<<<512, 256, 0, stream>>>(x, ws);
    k_prepw1<<<17, 256, 0, stream>>>(
        (const float*)d_in[1], (const float*)d_in[2], (const float*)d_in[3],
        (const float*)d_in[4], (const float*)d_in[5], (const float*)d_in[6],
        (const float*)d_in[7], (const float*)d_in[8], (const float*)d_in[9], ws);
    k_conv1<<<2048, 256, 0, stream>>>(x, ws, p1);
    k_stat2red<<<64, 256, 0, stream>>>(ws);
    k_prepw2<<<400, 256, 0, stream>>>(
        (const float*)d_in[10], (const float*)d_in[11], (const float*)d_in[12],
        (const float*)d_in[13], (const float*)d_in[14], (const float*)d_in[15],
        (const float*)d_in[16], (const float*)d_in[17], (const float*)d_in[18], ws, wp2);
    k_conv2<<<683, 384, 0, stream>>>((const ushort*)p1, (const ushort*)wp2, ws, p2);
    k_statl<<<64, 256, 0, stream>>>(p2, ws);
    k_prepwl<<<41, 256, 0, stream>>>(
        (const float*)d_in[19], (const float*)d_in[20], (const float*)d_in[21],
        (const float*)d_in[22], (const float*)d_in[23], (const float*)d_in[24],
        (const float*)d_in[25], (const float*)d_in[26], (const float*)d_in[27], ws);
    k_linear<<<512, 256, 0, stream>>>(p2, ws, out);
}

// Round 9
// 196.060 us; speedup vs baseline: 1.1296x; 1.1296x over previous
//
#include <hip/hip_runtime.h>
#include <hip/hip_bf16.h>

typedef float v4f __attribute__((ext_vector_type(4)));
typedef short v8s __attribute__((ext_vector_type(8)));

// ---- workspace layout ----
// float indices:
#define WS_STAT2   0        // 64   conv2 per-ic mean-of-max
#define WS_STATL   64       // 1024 (unused now; kept for layout stability)
#define WS_B1      1088     // 64
#define WS_B2      1152     // 64
#define WS_WL      1216     // 10240
#define WS_BL      11456    // 10
#define WS_IMAX    11520    // 2048 per-image max|x|
// byte offsets:
#define WS_W1F_B   54272    // 4096 bf16 conv1 weight frags [ot][q][m16][j], oc = m16*4+ot
#define WS_WP2_B   62464    // 25*64*64 bf16 conv2 weights, fragment order [uv][kc][ot][quad][m16][j]
#define WS_P1_B    267264   // 2048*144*64 bf16 pooled1 NHWC
#define WS_P2_B    38016000 // 2048*1024 fp32 pooled2
// scratch aliases (stream-ordered reuse, no extra footprint):
#define WS_C1MAX_F 9504000  // = P2 base as float idx; conv1 per-image ch-max [n][64]
#define WS_LPART_F 66816    // = P1 base as float idx; statl partials [128][1024] (P1 dead at statl time)

// per-image max|x|: 512 blocks x 4 waves, wave = 1 image.
__global__ void k_stat1(const float* __restrict__ x, float* ws) {
    int tid = threadIdx.x;
    int wv = tid >> 6, lane = tid & 63;
    int n = blockIdx.x * 4 + wv;
    const float* p = x + n * 784;
    float m = 0.f;
    for (int i = lane; i < 784; i += 64) m = fmaxf(m, fabsf(p[i]));
#pragma unroll
    for (int off = 32; off; off >>= 1) m = fmaxf(m, __shfl_xor(m, off, 64));
    if (lane == 0) ws[WS_IMAX + n] = m;
}

// conv1 SCINOL weights -> bf16 B-fragments [ot][q][m16][j] with oc = m16*4+ot
__global__ void k_prepw1(const float* __restrict__ w0, const float* __restrict__ S2,
                         const float* __restrict__ G, const float* __restrict__ eta,
                         const float* __restrict__ wM,
                         const float* __restrict__ b0, const float* __restrict__ bS2,
                         const float* __restrict__ bG, const float* __restrict__ beta,
                         float* ws) {
    __shared__ float red[256];
    int tid = threadIdx.x;
    float p = 0.f;
    for (int i = tid; i < 2048; i += 256) p += ws[WS_IMAX + i];
    red[tid] = p;
    __syncthreads();
    for (int s = 128; s > 0; s >>= 1) {
        if (tid < s) red[tid] += red[tid + s];
        __syncthreads();
    }
    float M = fmaxf(red[0] * (1.f / 2048.f), wM[0]);

    int i = blockIdx.x * 256 + tid;
    if (i < 4096) {
        int j = i & 7, m16 = (i >> 3) & 15, q = (i >> 7) & 3, ot = i >> 9;
        int tap = q * 8 + j, oc = m16 * 4 + ot;
        float v = 0.f;
        if (tap < 25) {
            int s = oc * 25 + tap;
            float g = G[s];
            float den = sqrtf(S2[s] + M * M);
            float inv = 1.f / den;
            float th = fminf(fmaxf(g * inv, -1.f), 1.f);
            v = w0[s] + ((g != 0.f) ? th * 0.5f * inv * eta[s] : 0.f);
        }
        ((__hip_bfloat16*)((char*)ws + WS_W1F_B))[i] = __float2bfloat16(v);
    } else if (i < 4160) {
        int c = i - 4096;
        float g = bG[c];
        float den = sqrtf(bS2[c] + 1.f);
        float inv = 1.f / den;
        float th = fminf(fmaxf(g * inv, -1.f), 1.f);
        ws[WS_B1 + c] = b0[c] + ((g != 0.f) ? th * 0.5f * inv * beta[c] : 0.f);
    }
}

// conv1 via MFMA implicit GEMM. Block = 256 thr (4 waves) = 1 image.
// Image staged as bf16 (rounding point unchanged -> identical numerics).
// Per-image channel maxima -> WS_C1MAX_F (plain stores; NO device atomics).
__global__ void __launch_bounds__(256)
k_conv1(const float* __restrict__ x, float* ws, __hip_bfloat16* __restrict__ pool1) {
    __shared__ __align__(16) ushort sXh[1024];   // 28x28 image as bf16 + zero pad
    __shared__ int sMax[64];
    int n = blockIdx.x, tid = threadIdx.x;
    int wv = tid >> 6, lane = tid & 63;
    int m16 = lane & 15, quad = lane >> 4;

    {   // stage image (784 floats -> bf16) + zero pad to 1024
        const float4* src = (const float4*)(x + (size_t)n * 784);
        float4 v = {0.f, 0.f, 0.f, 0.f};
        if (tid < 196) v = src[tid];
        ushort4 h;
        h.x = __bfloat16_as_ushort(__float2bfloat16(v.x));
        h.y = __bfloat16_as_ushort(__float2bfloat16(v.y));
        h.z = __bfloat16_as_ushort(__float2bfloat16(v.z));
        h.w = __bfloat16_as_ushort(__float2bfloat16(v.w));
        ((ushort4*)sXh)[tid] = h;
    }
    if (tid < 64) sMax[tid] = 0;

    const ushort* wfrag = (const ushort*)((const char*)ws + WS_W1F_B);
    v8s bfr[4];
#pragma unroll
    for (int ot = 0; ot < 4; ++ot)
        bfr[ot] = *(const v8s*)(wfrag + ((ot * 4 + quad) * 16 + m16) * 8);
    float4 bias = *(const float4*)(ws + WS_B1 + m16 * 4);

    int dj[8];
#pragma unroll
    for (int j = 0; j < 8; ++j) {
        int tap = quad * 8 + j;
        int u = (tap * 13) >> 6;
        dj[j] = tap + 23 * u;
    }

    int W0 = wv * 36 + (m16 >> 2);
    int wy = (W0 * 171) >> 11;
    int wx = W0 - wy * 12;
    int coff = 28 * ((m16 >> 1) & 1) + (m16 & 1);

    __syncthreads();

    float vmax[4] = {0.f, 0.f, 0.f, 0.f};
    ushort* op = (ushort*)(pool1 + (size_t)n * 9216);

    ushort g[8];
    {
        int base = 56 * wy + 2 * wx + coff;
#pragma unroll
        for (int j = 0; j < 8; ++j) g[j] = sXh[base + dj[j]];
    }
    for (int mt = 0; mt < 9; ++mt) {
        union { v8s v; ushort us[8]; } ua;
#pragma unroll
        for (int j = 0; j < 8; ++j) ua.us[j] = g[j];

        wx += 4;
        if (wx >= 12) { wx -= 12; ++wy; }
        if (mt < 8) {
            int nb = 56 * wy + 2 * wx + coff;
#pragma unroll
            for (int j = 0; j < 8; ++j) g[j] = sXh[nb + dj[j]];
        }

        v4f z = {0.f, 0.f, 0.f, 0.f};
        v4f acc[4];
#pragma unroll
        for (int ot = 0; ot < 4; ++ot)
            acc[ot] = __builtin_amdgcn_mfma_f32_16x16x32_bf16(ua.v, bfr[ot], z, 0, 0, 0);

        int Wd = (wv * 9 + mt) * 4 + quad;
        ushort4 pk;
#pragma unroll
        for (int ot = 0; ot < 4; ++ot) {
            v4f a = acc[ot];
            float m = fmaxf(fmaxf(a[0], a[1]), fmaxf(a[2], a[3]));
            float pv = fmaxf(m + bias[ot], 0.f);
            vmax[ot] = fmaxf(vmax[ot], pv);
            ((ushort*)&pk)[ot] = __bfloat16_as_ushort(__float2bfloat16(pv));
        }
        *(ushort4*)(op + Wd * 64 + m16 * 4) = pk;
    }

#pragma unroll
    for (int ot = 0; ot < 4; ++ot) {
        float m = vmax[ot];
        m = fmaxf(m, __shfl_xor(m, 16, 64));
        m = fmaxf(m, __shfl_xor(m, 32, 64));
        if (lane < 16) atomicMax(&sMax[lane * 4 + ot], __float_as_int(m));
    }
    __syncthreads();
    if (tid < 64) ws[WS_C1MAX_F + n * 64 + tid] = __int_as_float(sMax[tid]);
}

// reduce conv1 per-image channel maxima -> per-channel batch mean. 64 blocks, 1/ch.
__global__ void k_stat2red(float* ws) {
    __shared__ float red[256];
    int c = blockIdx.x, t = threadIdx.x;
    float s = 0.f;
    for (int n = t; n < 2048; n += 256) s += ws[WS_C1MAX_F + n * 64 + c];
    red[t] = s;
    __syncthreads();
    for (int k = 128; k > 0; k >>= 1) {
        if (t < k) red[t] += red[t + k];
        __syncthreads();
    }
    if (t == 0) ws[WS_STAT2 + c] = red[0] * (1.f / 2048.f);
}

// conv2 SCINOL weights -> bf16 in MFMA fragment order [uv][kc][ot][quad][m16][j]
__global__ void k_prepw2(const float* __restrict__ w0, const float* __restrict__ S2,
                         const float* __restrict__ G, const float* __restrict__ eta,
                         const float* __restrict__ wM,
                         const float* __restrict__ b0, const float* __restrict__ bS2,
                         const float* __restrict__ bG, const float* __restrict__ beta,
                         float* ws, __hip_bfloat16* __restrict__ wp2) {
    int i = blockIdx.x * 256 + threadIdx.x;  // exactly 102400
    int j = i & 7, m16 = (i >> 3) & 15, quad = (i >> 7) & 3;
    int ot = (i >> 9) & 3, kc = (i >> 11) & 1, uv = i >> 12;
    int oc = ot * 16 + m16, ic = kc * 32 + quad * 8 + j;
    int s = oc * 1600 + ic * 25 + uv;
    float M = fmaxf(ws[WS_STAT2 + ic], wM[ic]);
    float g = G[s];
    float den = sqrtf(S2[s] + M * M);
    float inv = 1.f / den;
    float th = fminf(fmaxf(g * inv, -1.f), 1.f);
    float v = w0[s] + ((g != 0.f) ? th * 0.5f * inv * eta[s] : 0.f);
    wp2[i] = __float2bfloat16(v);
    if (blockIdx.x == 0 && threadIdx.x < 64) {
        int c = threadIdx.x;
        float gb = bG[c];
        float den2 = sqrtf(bS2[c] + 1.f);
        float inv2 = 1.f / den2;
        float th2 = fminf(fmaxf(gb * inv2, -1.f), 1.f);
        ws[WS_B2 + c] = b0[c] + ((gb != 0.f) ? th2 * 0.5f * inv2 * beta[c] : 0.f);
    }
}

// ---- conv2 v9 pipeline macros (all indices compile-time; rule #20) ----

// read A(uvi) fragments into named 8-v8s set (idx = kc*4+pt); sImg is read-only
// after the prologue, so these ds_reads legally stay in flight across barriers.
#define LOADA(Aset, uvi) do {                                                  \
    int u_ = (uvi) / 5, v_ = (uvi) % 5;                                        \
    int r0_ = rbase + u_ * 12 + v_;                                            \
    _Pragma("unroll")                                                          \
    for (int kc_ = 0; kc_ < 2; ++kc_)                                          \
        _Pragma("unroll")                                                      \
        for (int pt_ = 0; pt_ < 4; ++pt_) {                                    \
            int row_ = r0_ + pt_ * 24;                                         \
            int rs_ = row_ & 7;                                                \
            Aset[kc_ * 4 + pt_] = *(const v8s*)(simg + row_ * 64 +             \
                                     (((kc_ * 4 + quad) ^ rs_) << 3));         \
        }                                                                      \
} while (0)

#define LOADPB() do {                                                          \
    _Pragma("unroll")                                                          \
    for (int q_ = 0; q_ < 8; ++q_)                                             \
        pB[q_] = *(const v8s*)(sB + q_ * 512 + lane * 8);                      \
} while (0)

#define DOMFMA(Aset) do {                                                      \
    _Pragma("unroll")                                                          \
    for (int kc_ = 0; kc_ < 2; ++kc_)                                          \
        _Pragma("unroll")                                                      \
        for (int pt_ = 0; pt_ < 4; ++pt_)                                      \
            _Pragma("unroll")                                                  \
            for (int ot_ = 0; ot_ < 4; ++ot_)                                  \
                acc[pt_][ot_] = __builtin_amdgcn_mfma_f32_16x16x32_bf16(       \
                    Aset[kc_ * 4 + pt_], pB[kc_ * 4 + ot_], acc[pt_][ot_],     \
                    0, 0, 0);                                                  \
} while (0)

// barrier: LDS ops retired (lgkmcnt(0)); vmcnt deliberately NOT drained —
// the global B prefetch stays in flight across barriers (T4). By barrier
// time the step's MFMAs have consumed pB and the A-prefetch ds_reads have
// retired, so the lgkmcnt wait is empty in steady state.
#define BAR_LDS() do {                                                         \
    asm volatile("s_waitcnt lgkmcnt(0)" ::: "memory");                         \
    __builtin_amdgcn_sched_barrier(0);                                         \
    __builtin_amdgcn_s_barrier();                                              \
    __builtin_amdgcn_sched_barrier(0);                                         \
} while (0)

// conv2 implicit GEMM, v9: round-6 dataflow (4 img/block LDS-swizzled, B
// block-shared in 8KB sB, 80KB total -> 2 blocks/CU, 8 waves/CU = grid cap)
// with the K-loop re-synced: raw s_barrier + lgkmcnt-only waits (T4) so the
// global B prefetch is NEVER drained at barriers; B prefetch 2 steps deep in
// named regs (ga/gb); A ds_reads hoisted 1 step ahead under the MFMA phase.
// MFMA accumulation order identical to rounds 0-7 -> bit-identical output.
__global__ void __launch_bounds__(256, 2)
k_conv2(const ushort* __restrict__ pool1, const ushort* __restrict__ wp2,
        const float* __restrict__ ws, float* __restrict__ pool2) {
    __shared__ __align__(16) ushort sImg[4 * 9216];  // 72KB: 4 images, swizzled
    __shared__ __align__(16) ushort sB[4096];        // 8KB: one uv of B frags
    int tid = threadIdx.x;
    int wv = tid >> 6, lane = tid & 63;
    int n0 = blockIdx.x * 4;

    {   // stage 4 images: per image 1152 uint4 chunks; (r,col) -> r*8 + (col^(r&7))
        const uint4* src = (const uint4*)(pool1 + (size_t)n0 * 9216);
        uint4* dst = (uint4*)sImg;
#pragma unroll
        for (int img = 0; img < 4; ++img) {
            int b = img * 1152;
#pragma unroll
            for (int i = 0; i < 4; ++i) {
                int c = tid + i * 256;          // 0..1023
                int r = c >> 3, col = c & 7;
                dst[b + r * 8 + (col ^ (r & 7))] = src[b + c];
            }
            if (tid < 128) {
                int c = 1024 + tid;             // 1024..1151
                int r = c >> 3, col = c & 7;
                dst[b + r * 8 + (col ^ (r & 7))] = src[b + c];
            }
        }
    }

    int m16 = lane & 15, quad = lane >> 4;
    int x0 = m16 & 7;
    int yb = m16 >> 3;
    int rbase = yb * 12 + x0;

    v4f acc[4][4];
#pragma unroll
    for (int i = 0; i < 4; ++i)
#pragma unroll
        for (int j = 0; j < 4; ++j) acc[i][j] = (v4f){0.f, 0.f, 0.f, 0.f};

    const uint4* bsrc = (const uint4*)wp2;
    uint4 g00 = bsrc[tid], g01 = bsrc[256 + tid];          // B(0)

    __syncthreads();                 // image staging complete (one-time full sync)

    ((uint4*)sB)[tid] = g00;
    ((uint4*)sB)[256 + tid] = g01;
    // deep prefetch: B(1) and B(2) into named reg sets (stay in flight)
    uint4 ga0 = bsrc[512 + tid],  ga1 = bsrc[768 + tid];   // B(1)
    uint4 gb0 = bsrc[1024 + tid], gb1 = bsrc[1280 + tid];  // B(2)

    const ushort* simg = sImg + wv * 9216;
    v8s Aa[8], Ab[8], pB[8];
    LOADA(Aa, 0);                    // A(0); sImg valid after the full sync

    BAR_LDS();                       // sB(0) visible; GB loads NOT drained

#pragma unroll 1
    for (int t = 0; t < 12; ++t) {
        int e = 2 * t;               // even step: sB holds B(e), A in Aa
        LOADPB();
        LOADA(Ab, e + 1);            // prefetch A for odd step
        DOMFMA(Aa);
        BAR_LDS();                   // all waves done reading sB(e)
        ((uint4*)sB)[tid] = ga0;     // publish B(e+1) (loaded 2 steps ago)
        ((uint4*)sB)[256 + tid] = ga1;
        if (e + 3 < 25) {            // issue B(e+3)
            const uint4* nb = bsrc + (e + 3) * 512;
            ga0 = nb[tid]; ga1 = nb[256 + tid];
        }
        BAR_LDS();                   // sB(e+1) visible

        // odd step: sB holds B(e+1), A in Ab
        LOADPB();
        LOADA(Aa, e + 2);            // prefetch A for next even step
        DOMFMA(Ab);
        BAR_LDS();
        ((uint4*)sB)[tid] = gb0;     // publish B(e+2)
        ((uint4*)sB)[256 + tid] = gb1;
        if (e + 4 < 25) {            // issue B(e+4)
            const uint4* nb = bsrc + (e + 4) * 512;
            gb0 = nb[tid]; gb1 = nb[256 + tid];
        }
        BAR_LDS();
    }
    // tail: step 24 (sB holds B(24), A in Aa)
    LOADPB();
    DOMFMA(Aa);

    // epilogue: bias + relu + 2x2 maxpool -> pooled2[n][oc*16+py*4+px] fp32
    int n = n0 + wv;
    float bv[4];
#pragma unroll
    for (int ot = 0; ot < 4; ++ot) bv[ot] = ws[WS_B2 + ot * 16 + m16];
    float* outp = pool2 + (size_t)n * 1024;
#pragma unroll
    for (int pt = 0; pt < 4; ++pt)
#pragma unroll
        for (int ot = 0; ot < 4; ++ot) {
            v4f a = acc[pt][ot];
            float m01 = fmaxf(a[0], a[1]);
            float m23 = fmaxf(a[2], a[3]);
            m01 = fmaxf(m01, __shfl_xor(m01, 32, 64));
            m23 = fmaxf(m23, __shfl_xor(m23, 32, 64));
            if (lane < 32) {
                int oc = ot * 16 + m16;
                int f = oc * 16 + pt * 4 + (quad & 1) * 2;
                outp[f] = fmaxf(m01 + bv[ot], 0.f);
                outp[f + 1] = fmaxf(m23 + bv[ot], 0.f);
            }
        }
}

// per-feature partial sums over batch; 128 blocks x 16 images, plain stores.
__global__ void k_statl(const float* __restrict__ pool2, float* ws) {
    int b = blockIdx.x, tid = threadIdx.x;
    float4 s = {0.f, 0.f, 0.f, 0.f};
    for (int im = 0; im < 16; ++im) {
        float4 v = ((const float4*)(pool2 + (size_t)(b * 16 + im) * 1024))[tid];
        s.x += v.x; s.y += v.y; s.z += v.z; s.w += v.w;
    }
    ((float4*)(ws + WS_LPART_F + b * 1024))[tid] = s;
}

// linear weights; folds the 128-partial statl reduction inline
__global__ void k_prepwl(const float* __restrict__ w0, const float* __restrict__ S2,
                         const float* __restrict__ G, const float* __restrict__ eta,
                         const float* __restrict__ wM,
                         const float* __restrict__ b0, const float* __restrict__ bS2,
                         const float* __restrict__ bG, const float* __restrict__ beta,
                         float* ws) {
    int i = blockIdx.x * 256 + threadIdx.x;
    if (i < 10240) {
        int f = i & 1023;
        float s = 0.f;
#pragma unroll 8
        for (int b = 0; b < 128; ++b) s += ws[WS_LPART_F + b * 1024 + f];
        float stat = s * (1.f / 2048.f);
        float M = fmaxf(wM[i], stat);
        float s2 = S2[i];
        float den = sqrtf(s2 + M * M);
        float inv = 1.f / den;
        float th = fminf(fmaxf(G[i] * inv, -1.f), 1.f);
        ws[WS_WL + i] = w0[i] + ((s2 != 0.f) ? th * 0.5f * inv * eta[i] : 0.f);  // cond = wS2 != 0
    } else if (i < 10250) {
        int c = i - 10240;
        float s2 = bS2[c];
        float den = sqrtf(s2 + 1.f);
        float inv = 1.f / den;
        float th = fminf(fmaxf(bG[c] * inv, -1.f), 1.f);
        ws[WS_BL + c] = b0[c] + ((s2 != 0.f) ? th * 0.5f * inv * beta[c] : 0.f);  // cond = bS2 != 0
    }
}

// (2048,1024) x (1024,10)^T + b: wave per image, lane-strided features
__global__ void k_linear(const float* __restrict__ pool2, const float* __restrict__ ws,
                         float* __restrict__ out) {
    int tid = threadIdx.x;
    int wv = tid >> 6, lane = tid & 63;
    int n = blockIdx.x * 4 + wv;
    const float* hp = pool2 + (size_t)n * 1024;
    float h[16];
#pragma unroll
    for (int j = 0; j < 16; ++j) h[j] = hp[j * 64 + lane];
    for (int oc = 0; oc < 10; ++oc) {
        const float* wp = ws + WS_WL + oc * 1024;
        float d = 0.f;
#pragma unroll
        for (int j = 0; j < 16; ++j) d = fmaf(h[j], wp[j * 64 + lane], d);
#pragma unroll
        for (int off = 32; off; off >>= 1) d += __shfl_xor(d, off, 64);
        if (lane == 0) out[n * 10 + oc] = d + ws[WS_BL + oc];
    }
}

extern "C" void kernel_launch(void* const* d_in, const int* in_sizes, int n_in,
                              void* d_out, int out_size, void* d_ws, size_t ws_size,
                              hipStream_t stream) {
    const float* x = (const float*)d_in[0];
    float* ws = (float*)d_ws;
    __hip_bfloat16* wp2 = (__hip_bfloat16*)((char*)d_ws + WS_WP2_B);
    __hip_bfloat16* p1 = (__hip_bfloat16*)((char*)d_ws + WS_P1_B);
    float* p2 = (float*)((char*)d_ws + WS_P2_B);
    float* out = (float*)d_out;

    k_stat1<<<512, 256, 0, stream>>>(x, ws);
    k_prepw1<<<17, 256, 0, stream>>>(
        (const float*)d_in[1], (const float*)d_in[2], (const float*)d_in[3],
        (const float*)d_in[4], (const float*)d_in[5], (const float*)d_in[6],
        (const float*)d_in[7], (const float*)d_in[8], (const float*)d_in[9], ws);
    k_conv1<<<2048, 256, 0, stream>>>(x, ws, p1);
    k_stat2red<<<64, 256, 0, stream>>>(ws);
    k_prepw2<<<400, 256, 0, stream>>>(
        (const float*)d_in[10], (const float*)d_in[11], (const float*)d_in[12],
        (const float*)d_in[13], (const float*)d_in[14], (const float*)d_in[15],
        (const float*)d_in[16], (const float*)d_in[17], (const float*)d_in[18], ws, wp2);
    k_conv2<<<512, 256, 0, stream>>>((const ushort*)p1, (const ushort*)wp2, ws, p2);
    k_statl<<<128, 256, 0, stream>>>(p2, ws);
    k_prepwl<<<41, 256, 0, stream>>>(
        (const float*)d_in[19], (const float*)d_in[20], (const float*)d_in[21],
        (const float*)d_in[22], (const float*)d_in[23], (const float*)d_in[24],
        (const float*)d_in[25], (const float*)d_in[26], (const float*)d_in[27], ws);
    k_linear<<<512, 256, 0, stream>>>(p2, ws, out);
}